// Round 3
// baseline (157.233 us; speedup 1.0000x reference)
//
#include <hip/hip_runtime.h>
#include <hip/hip_bf16.h>

// Established: inputs f32, output f32. Threshold 0.038; absmax floor 0.0078 (1 bf16 ulp).
// Math: y = (rec + DELTA*(cat(du,u)@Bw^T)) @ Cw^T,  rec = h + 0.005*(W@h - W^T@h)
// (expm/inv series truncated at X^1; X^2+ terms <4e-5, validated r3-r9).
// r9: intra-kernel fusion catastrophic. r11 (reg-direct, low grid): REGRESSED -> occupancy.
// r12: gl_lds width-16 staging + both-sides XOR swizzle GEMM cores; BUT k2 launched 2x too
//   many tiles (mt 0..31 on a 512-row problem -> OOB writes + doubled work) and Cw cvt sat
//   on k1's critical path. r13: k2 fixed to 512 GEMM blocks + 512 overlapped Cw-cvt blocks
//   (r0 arrangement); k1's two full passes over W fused into one (wh row-dots now computed
//   as 8 col-chunk partials whp via per-wave shfl reduce, summed in k2 epilogue).

#define B_SZ 512
#define U_DIM 1024
#define DU_DIM 512
#define H_DIM 2048
#define Y_DIM 1024
#define K_CAT 1536
#define DELTA_F 0.01f

typedef __hip_bfloat16 bf16;
using bf16x8f = __attribute__((ext_vector_type(8))) short;
using f32x4   = __attribute__((ext_vector_type(4))) float;

__device__ __forceinline__ short f2bs(float x) {
  union { bf16 b; short s; } u; u.b = __float2bfloat16(x); return u.s;
}
__device__ __forceinline__ int4 pack8(const float4 v0, const float4 v1) {
  union { short s[8]; int4 i; } o;
  o.s[0] = f2bs(v0.x); o.s[1] = f2bs(v0.y); o.s[2] = f2bs(v0.z); o.s[3] = f2bs(v0.w);
  o.s[4] = f2bs(v1.x); o.s[5] = f2bs(v1.y); o.s[6] = f2bs(v1.z); o.s[7] = f2bs(v1.w);
  return o.i;
}

// async 16B global->LDS. LDS dest is wave-uniform base + lane*16 (linear in tid).
__device__ __forceinline__ void stage16(const void* g, void* l) {
  __builtin_amdgcn_global_load_lds(
      (const __attribute__((address_space(1))) unsigned int*)g,
      (__attribute__((address_space(3))) unsigned int*)l, 16, 0, 0);
}

#define NB   (H_DIM * K_CAT / 8)   // 393216 Bw granules
#define NCAT (B_SZ * K_CAT / 8)    //  98304 cat granules
#define NC   (Y_DIM * H_DIM / 8)   // 262144 Cw granules

// ---------------- K1: fused W pass (0..255) + Bw/cat cvt (256..1023) ----------------
// Block (rowg,colg) streams W[rowg*64 .. +64][colg*256 .. +256] ONCE:
//   wtp[rowg][k]      = sum_i W[r0+i][k] * h[r0+i]         (col partials, per thread)
//   whp[colg][r0+i]   = sum_k W[r0+i][k] * h[k]            (row partials, wave shfl-reduce)
__global__ __launch_bounds__(256) void k1(const float* __restrict__ W, const float* __restrict__ h,
                                          const float* __restrict__ Bw, const float* __restrict__ du,
                                          const float* __restrict__ u, float* __restrict__ whp,
                                          float* __restrict__ wtp, short* __restrict__ Bwb,
                                          short* __restrict__ catb) {
  const int b = blockIdx.x;
  if (b < 256) {
    const int rowg = b >> 3, colg = b & 7;
    const int r0 = rowg * 64;
    const int k = colg * 256 + threadIdx.x;
    const int lane = threadIdx.x & 63, wave = threadIdx.x >> 6;
    __shared__ float rowred[64][4];
    const float* base = W + (size_t)r0 * H_DIM + k;
    const float hk = h[k];
    float scol = 0.f;
#pragma unroll 8
    for (int i = 0; i < 64; i++) {
      float v = base[(size_t)i * H_DIM];
      scol += v * h[r0 + i];
      float p = v * hk;
#pragma unroll
      for (int off = 32; off > 0; off >>= 1) p += __shfl_down(p, off);
      if (lane == 0) rowred[i][wave] = p;
    }
    wtp[rowg * H_DIM + k] = scol;
    __syncthreads();
    if (threadIdx.x < 64) {
      float s = rowred[threadIdx.x][0] + rowred[threadIdx.x][1] +
                rowred[threadIdx.x][2] + rowred[threadIdx.x][3];
      whp[colg * H_DIM + r0 + threadIdx.x] = s;
    }
  } else {  // Bw, cat(du,u) -> bf16
    for (int g = (b - 256) * 256 + threadIdx.x; g < NB + NCAT; g += 768 * 256) {
      if (g < NB) {
        int e = g * 8;
        *(int4*)(Bwb + e) = pack8(*(const float4*)(Bw + e), *(const float4*)(Bw + e + 4));
      } else {
        int g2 = g - NB;
        int row = g2 / 192, c = g2 - row * 192;  // 192 granules per 1536-wide row
        const float* src = (c < 64) ? du + (size_t)row * DU_DIM + c * 8
                                    : u + (size_t)row * U_DIM + (c - 64) * 8;
        *(int4*)(catb + (size_t)row * K_CAT + c * 8) =
            pack8(*(const float4*)src, *(const float4*)(src + 4));
      }
    }
  }
}

#define MFMA __builtin_amdgcn_mfma_f32_16x16x32_bf16

// ---------------- K2: 512 GEMM blocks (32x64 tiles) + 512 Cw-cvt blocks (overlapped) ----------------
// bb = bf16(rec + DELTA*(catb @ Bwb^T)); 2-phase LDS dbuf, gl_lds staging, XOR granule swizzle.
__global__ __launch_bounds__(256) void k2(const short* __restrict__ catb, const short* __restrict__ Bwb,
                                          const float* __restrict__ h, const float* __restrict__ whp,
                                          const float* __restrict__ wtp, short* __restrict__ bb,
                                          const float* __restrict__ Cw, short* __restrict__ Cwb) {
  __shared__ __align__(16) short lds[2 * 6144];  // per buf: A 32x64 (2048) + B 64x64 (4096)
  __shared__ float recf[64];
  const int b = blockIdx.x;
  if (b >= 512) {  // Cw -> bf16 (consumed only by k3; hidden behind GEMM blocks)
    int g0 = (b - 512) * 256 + threadIdx.x;  // NC = 262144 = 2 * 131072
    int e = g0 * 8;
    *(int4*)(Cwb + e) = pack8(*(const float4*)(Cw + e), *(const float4*)(Cw + e + 4));
    e = (g0 + 131072) * 8;
    *(int4*)(Cwb + e) = pack8(*(const float4*)(Cw + e), *(const float4*)(Cw + e + 4));
    return;
  }
  const int tid = threadIdx.x;
  const int lane = tid & 63, wave = tid >> 6;
  const int wm = wave >> 1, wn = wave & 1;
  const int mt = b >> 5, nt = b & 31;  // 16 x 32 tiles of 32x64
  const int row0 = mt * 32, col0 = nt * 64;
  const int rA = tid >> 3, gA = tid & 7;
  const int sA = (gA ^ (rA & 7)) * 8;  // pre-swizzled source granule; (r+32)&7 == r&7
  const short* srcA  = catb + (size_t)(row0 + rA) * K_CAT + sA;
  const short* srcB1 = Bwb + (size_t)(col0 + rA) * K_CAT + sA;
  const short* srcB2 = Bwb + (size_t)(col0 + 32 + rA) * K_CAT + sA;
  const int NT = K_CAT / 64;
  const int rm = lane & 15, quad = lane >> 4;
  f32x4 acc[2] = {};
  stage16(srcA,  lds + tid * 8);
  stage16(srcB1, lds + 2048 + tid * 8);
  stage16(srcB2, lds + 4096 + tid * 8);
  __syncthreads();
  const int ra = wm * 16 + rm;
  const int rb0 = wn * 32 + rm, rb1 = wn * 32 + 16 + rm;
  const int oa = ra * 64, ob0 = rb0 * 64, ob1 = rb1 * 64;
  const int xa = (ra & 7), xb0 = (rb0 & 7), xb1 = (rb1 & 7);
  for (int kt = 0; kt < NT; kt++) {
    const int cur = kt & 1;
    if (kt + 1 < NT) {
      const int o = (kt + 1) * 64;
      short* nb = lds + (cur ^ 1) * 6144;
      stage16(srcA + o,  nb + tid * 8);
      stage16(srcB1 + o, nb + 2048 + tid * 8);
      stage16(srcB2 + o, nb + 4096 + tid * 8);
    }
    const short* Ac = lds + cur * 6144;
    const short* Bc = Ac + 2048;
#pragma unroll
    for (int ks = 0; ks < 2; ks++) {
      const int kg = ks * 4 + quad;
      bf16x8f af  = *(const bf16x8f*)&Ac[oa + ((kg ^ xa) << 3)];
      bf16x8f bf0 = *(const bf16x8f*)&Bc[ob0 + ((kg ^ xb0) << 3)];
      bf16x8f bf1 = *(const bf16x8f*)&Bc[ob1 + ((kg ^ xb1) << 3)];
      acc[0] = MFMA(af, bf0, acc[0], 0, 0, 0);
      acc[1] = MFMA(af, bf1, acc[1], 0, 0, 0);
    }
    if (kt + 1 < NT) __syncthreads();
  }
  if (tid < 64) {  // rec[c] = h[c] + 0.005*(sum_g whp[g][c] - sum_p wtp[p][c])
    int gc = col0 + tid;
    float sw = 0.f, st = 0.f;
#pragma unroll
    for (int g = 0; g < 8; g++) sw += whp[g * H_DIM + gc];
#pragma unroll
    for (int p = 0; p < 32; p++) st += wtp[p * H_DIM + gc];
    recf[tid] = h[gc] + 0.005f * (sw - st);
  }
  __syncthreads();
#pragma unroll
  for (int j = 0; j < 2; j++) {
    int gc = col0 + wn * 32 + 16 * j + rm;
#pragma unroll
    for (int r = 0; r < 4; r++) {
      int gr = row0 + wm * 16 + quad * 4 + r;
      bb[(size_t)gr * H_DIM + gc] = f2bs(recf[gc - col0] + DELTA_F * acc[j][r]);
    }
  }
}

// ---------------- K3: 512 blocks, 32x32 tiles: y = bb @ Cwb^T (f32 out) ----------------
__global__ __launch_bounds__(256) void k3(const short* __restrict__ A, const short* __restrict__ B,
                                          float* __restrict__ y) {
  __shared__ __align__(16) short lds[2 * 4096];  // per buf: A 32x64 (2048) + B 32x64 (2048)
  const int tid = threadIdx.x;
  const int lane = tid & 63, wave = tid >> 6;
  const int wm = wave >> 1, wn = wave & 1;
  const int mt = blockIdx.x >> 5, nt = blockIdx.x & 31;  // 16 x 32 tiles of 32x32
  const int row0 = mt * 32, col0 = nt * 32;
  const int rA = tid >> 3, gA = tid & 7;
  const int sA = (gA ^ (rA & 7)) * 8;
  const short* srcA = A + (size_t)(row0 + rA) * H_DIM + sA;
  const short* srcB = B + (size_t)(col0 + rA) * H_DIM + sA;
  const int NT = H_DIM / 64;
  const int rm = lane & 15, quad = lane >> 4;
  f32x4 acc = {};
  stage16(srcA, lds + tid * 8);
  stage16(srcB, lds + 2048 + tid * 8);
  __syncthreads();
  const int ra = wm * 16 + rm, rb = wn * 16 + rm;
  const int oa = ra * 64, ob = rb * 64;
  const int xa = (ra & 7), xb = (rb & 7);
  for (int kt = 0; kt < NT; kt++) {
    const int cur = kt & 1;
    if (kt + 1 < NT) {
      const int o = (kt + 1) * 64;
      short* nb = lds + (cur ^ 1) * 4096;
      stage16(srcA + o, nb + tid * 8);
      stage16(srcB + o, nb + 2048 + tid * 8);
    }
    const short* Ac = lds + cur * 4096;
    const short* Bc = Ac + 2048;
#pragma unroll
    for (int ks = 0; ks < 2; ks++) {
      const int kg = ks * 4 + quad;
      bf16x8f af = *(const bf16x8f*)&Ac[oa + ((kg ^ xa) << 3)];
      bf16x8f bf = *(const bf16x8f*)&Bc[ob + ((kg ^ xb) << 3)];
      acc = MFMA(af, bf, acc, 0, 0, 0);
    }
    if (kt + 1 < NT) __syncthreads();
  }
  int gc = col0 + wn * 16 + rm;
#pragma unroll
  for (int r = 0; r < 4; r++) {
    int gr = row0 + wm * 16 + quad * 4 + r;
    y[(size_t)gr * Y_DIM + gc] = acc[r];
  }
}

extern "C" void kernel_launch(void* const* d_in, const int* in_sizes, int n_in,
                              void* d_out, int out_size, void* d_ws, size_t ws_size,
                              hipStream_t stream) {
  const float* u  = (const float*)d_in[0];
  const float* du = (const float*)d_in[1];
  const float* W  = (const float*)d_in[2];
  const float* Bw = (const float*)d_in[3];
  const float* Cw = (const float*)d_in[4];
  const float* h  = (const float*)d_in[5];
  float* y = (float*)d_out;

  char* w = (char*)d_ws;
  size_t off = 0;
  short* Bwb  = (short*)(w + off); off += (size_t)H_DIM * K_CAT * sizeof(short);  // 6 MB
  short* Cwb  = (short*)(w + off); off += (size_t)Y_DIM * H_DIM * sizeof(short);  // 4 MB
  short* bb   = (short*)(w + off); off += (size_t)B_SZ * H_DIM * sizeof(short);   // 2 MB
  short* catb = (short*)(w + off); off += (size_t)B_SZ * K_CAT * sizeof(short);   // 1.5 MB
  float* whp  = (float*)(w + off); off += 8 * H_DIM * sizeof(float);              // 64 KB
  float* wtp  = (float*)(w + off); off += 32 * H_DIM * sizeof(float);             // 256 KB
  if (ws_size < off) return;

  k1<<<1024, 256, 0, stream>>>(W, h, Bw, du, u, whp, wtp, Bwb, catb);
  k2<<<1024, 256, 0, stream>>>(catb, Bwb, h, whp, wtp, bb, Cw, Cwb);
  k3<<<512, 256, 0, stream>>>(bb, Cwb, y);
}

// Round 4
// 123.507 us; speedup vs baseline: 1.2731x; 1.2731x over previous
//
#include <hip/hip_runtime.h>
#include <hip/hip_bf16.h>

// Established: inputs f32, output f32. Threshold 0.038; absmax floor 0.0078 (1 bf16 ulp).
// Math: y = (rec + DELTA*(cat(du,u)@Bw^T)) @ Cw^T,  rec = h + 0.005*(W@h - W^T@h)
// (expm/inv series truncated at X^1; X^2+ terms <4e-5, validated r3-r9).
// r9: intra-kernel fusion catastrophic. r11: reg-direct low-grid GEMM regressed (occupancy).
// r13: fused single-pass W (per-row shfl chains) = 46.8us @ 524 GB/s, latency-serialized
//   -> REVERTED. Two-pass W (wh row-dots + wtp col-partials) is L3-absorbed and fast (r0).
// r14 = r0 k1 (wh 512 / wtp 256 / Bw+cat cvt 256) + r12/r13 k2,k3 (gl_lds width-16 staging,
//   both-sides XOR granule swizzle, correct 512-tile k2 grid, Cw cvt overlapped in k2).

#define B_SZ 512
#define U_DIM 1024
#define DU_DIM 512
#define H_DIM 2048
#define Y_DIM 1024
#define K_CAT 1536
#define DELTA_F 0.01f

typedef __hip_bfloat16 bf16;
using bf16x8f = __attribute__((ext_vector_type(8))) short;
using f32x4   = __attribute__((ext_vector_type(4))) float;

__device__ __forceinline__ short f2bs(float x) {
  union { bf16 b; short s; } u; u.b = __float2bfloat16(x); return u.s;
}
__device__ __forceinline__ int4 pack8(const float4 v0, const float4 v1) {
  union { short s[8]; int4 i; } o;
  o.s[0] = f2bs(v0.x); o.s[1] = f2bs(v0.y); o.s[2] = f2bs(v0.z); o.s[3] = f2bs(v0.w);
  o.s[4] = f2bs(v1.x); o.s[5] = f2bs(v1.y); o.s[6] = f2bs(v1.z); o.s[7] = f2bs(v1.w);
  return o.i;
}

// async 16B global->LDS. LDS dest is wave-uniform base + lane*16 (linear in tid).
__device__ __forceinline__ void stage16(const void* g, void* l) {
  __builtin_amdgcn_global_load_lds(
      (const __attribute__((address_space(1))) unsigned int*)g,
      (__attribute__((address_space(3))) unsigned int*)l, 16, 0, 0);
}

#define NB   (H_DIM * K_CAT / 8)   // 393216 Bw granules
#define NCAT (B_SZ * K_CAT / 8)    //  98304 cat granules
#define NC   (Y_DIM * H_DIM / 8)   // 262144 Cw granules

// ---------------- K1: wh (0..511), wtp partials (512..767), Bw+cat cvt (768..1023) ----------------
__global__ __launch_bounds__(256) void k1(const float* __restrict__ W, const float* __restrict__ h,
                                          const float* __restrict__ Bw, const float* __restrict__ du,
                                          const float* __restrict__ u, float* __restrict__ wh,
                                          float* __restrict__ wtp, short* __restrict__ Bwb,
                                          short* __restrict__ catb) {
  const int b = blockIdx.x;
  if (b < 512) {  // wh[row] = dot(W[row,:], h)   (one shfl-reduce per ROW, at the end)
    const int lane = threadIdx.x & 63, wave = threadIdx.x >> 6;
    const int row = b * 4 + wave;
    const float* wr = W + (size_t)row * H_DIM;
    float s = 0.f;
#pragma unroll
    for (int it = 0; it < 8; it++) {
      int k = it * 256 + lane * 4;
      float4 a = *(const float4*)(wr + k);
      float4 hv = *(const float4*)(h + k);
      s += a.x * hv.x + a.y * hv.y + a.z * hv.z + a.w * hv.w;
    }
#pragma unroll
    for (int off = 32; off > 0; off >>= 1) s += __shfl_down(s, off);
    if (lane == 0) wh[row] = s;
  } else if (b < 768) {  // wtp[rowg][k] = sum over 64-row chunk of W[i][k]*h[i]  (no shfls)
    const int e = b - 512;
    const int colg = e & 7, rowg = e >> 3;
    const int k = colg * 256 + threadIdx.x;
    float s = 0.f;
    const float* base = W + (size_t)rowg * 64 * H_DIM + k;
#pragma unroll 8
    for (int i = 0; i < 64; i++) s += base[(size_t)i * H_DIM] * h[rowg * 64 + i];
    wtp[rowg * H_DIM + k] = s;
  } else {  // Bw, cat(du,u) -> bf16
    for (int g = (b - 768) * 256 + threadIdx.x; g < NB + NCAT; g += 256 * 256) {
      if (g < NB) {
        int e = g * 8;
        *(int4*)(Bwb + e) = pack8(*(const float4*)(Bw + e), *(const float4*)(Bw + e + 4));
      } else {
        int g2 = g - NB;
        int row = g2 / 192, c = g2 - row * 192;  // 192 granules per 1536-wide row
        const float* src = (c < 64) ? du + (size_t)row * DU_DIM + c * 8
                                    : u + (size_t)row * U_DIM + (c - 64) * 8;
        *(int4*)(catb + (size_t)row * K_CAT + c * 8) =
            pack8(*(const float4*)src, *(const float4*)(src + 4));
      }
    }
  }
}

#define MFMA __builtin_amdgcn_mfma_f32_16x16x32_bf16

// ---------------- K2: 512 GEMM blocks (32x64 tiles) + 512 Cw-cvt blocks (overlapped) ----------------
// bb = bf16(rec + DELTA*(catb @ Bwb^T)); 2-phase LDS dbuf, gl_lds staging, XOR granule swizzle.
__global__ __launch_bounds__(256) void k2(const short* __restrict__ catb, const short* __restrict__ Bwb,
                                          const float* __restrict__ h, const float* __restrict__ wh,
                                          const float* __restrict__ wtp, short* __restrict__ bb,
                                          const float* __restrict__ Cw, short* __restrict__ Cwb) {
  __shared__ __align__(16) short lds[2 * 6144];  // per buf: A 32x64 (2048) + B 64x64 (4096)
  __shared__ float recf[64];
  const int b = blockIdx.x;
  if (b >= 512) {  // Cw -> bf16 (consumed only by k3; hidden behind GEMM blocks)
    int g0 = (b - 512) * 256 + threadIdx.x;  // NC = 262144 = 2 * 131072
    int e = g0 * 8;
    *(int4*)(Cwb + e) = pack8(*(const float4*)(Cw + e), *(const float4*)(Cw + e + 4));
    e = (g0 + 131072) * 8;
    *(int4*)(Cwb + e) = pack8(*(const float4*)(Cw + e), *(const float4*)(Cw + e + 4));
    return;
  }
  const int tid = threadIdx.x;
  const int lane = tid & 63, wave = tid >> 6;
  const int wm = wave >> 1, wn = wave & 1;
  const int mt = b >> 5, nt = b & 31;  // 16 x 32 tiles of 32x64
  const int row0 = mt * 32, col0 = nt * 64;
  const int rA = tid >> 3, gA = tid & 7;
  const int sA = (gA ^ (rA & 7)) * 8;  // pre-swizzled source granule; (r+32)&7 == r&7
  const short* srcA  = catb + (size_t)(row0 + rA) * K_CAT + sA;
  const short* srcB1 = Bwb + (size_t)(col0 + rA) * K_CAT + sA;
  const short* srcB2 = Bwb + (size_t)(col0 + 32 + rA) * K_CAT + sA;
  const int NT = K_CAT / 64;
  const int rm = lane & 15, quad = lane >> 4;
  f32x4 acc[2] = {};
  stage16(srcA,  lds + tid * 8);
  stage16(srcB1, lds + 2048 + tid * 8);
  stage16(srcB2, lds + 4096 + tid * 8);
  __syncthreads();
  const int ra = wm * 16 + rm;
  const int rb0 = wn * 32 + rm, rb1 = wn * 32 + 16 + rm;
  const int oa = ra * 64, ob0 = rb0 * 64, ob1 = rb1 * 64;
  const int xa = (ra & 7), xb0 = (rb0 & 7), xb1 = (rb1 & 7);
  for (int kt = 0; kt < NT; kt++) {
    const int cur = kt & 1;
    if (kt + 1 < NT) {
      const int o = (kt + 1) * 64;
      short* nb = lds + (cur ^ 1) * 6144;
      stage16(srcA + o,  nb + tid * 8);
      stage16(srcB1 + o, nb + 2048 + tid * 8);
      stage16(srcB2 + o, nb + 4096 + tid * 8);
    }
    const short* Ac = lds + cur * 6144;
    const short* Bc = Ac + 2048;
#pragma unroll
    for (int ks = 0; ks < 2; ks++) {
      const int kg = ks * 4 + quad;
      bf16x8f af  = *(const bf16x8f*)&Ac[oa + ((kg ^ xa) << 3)];
      bf16x8f bf0 = *(const bf16x8f*)&Bc[ob0 + ((kg ^ xb0) << 3)];
      bf16x8f bf1 = *(const bf16x8f*)&Bc[ob1 + ((kg ^ xb1) << 3)];
      acc[0] = MFMA(af, bf0, acc[0], 0, 0, 0);
      acc[1] = MFMA(af, bf1, acc[1], 0, 0, 0);
    }
    if (kt + 1 < NT) __syncthreads();
  }
  if (tid < 64) {  // rec[c] = h[c] + 0.005*(wh[c] - sum_p wtp[p][c])
    int gc = col0 + tid;
    float s = 0.f;
#pragma unroll
    for (int p = 0; p < 32; p++) s += wtp[p * H_DIM + gc];
    recf[tid] = h[gc] + 0.005f * (wh[gc] - s);
  }
  __syncthreads();
#pragma unroll
  for (int j = 0; j < 2; j++) {
    int gc = col0 + wn * 32 + 16 * j + rm;
#pragma unroll
    for (int r = 0; r < 4; r++) {
      int gr = row0 + wm * 16 + quad * 4 + r;
      bb[(size_t)gr * H_DIM + gc] = f2bs(recf[gc - col0] + DELTA_F * acc[j][r]);
    }
  }
}

// ---------------- K3: 512 blocks, 32x32 tiles: y = bb @ Cwb^T (f32 out) ----------------
__global__ __launch_bounds__(256) void k3(const short* __restrict__ A, const short* __restrict__ B,
                                          float* __restrict__ y) {
  __shared__ __align__(16) short lds[2 * 4096];  // per buf: A 32x64 (2048) + B 32x64 (2048)
  const int tid = threadIdx.x;
  const int lane = tid & 63, wave = tid >> 6;
  const int wm = wave >> 1, wn = wave & 1;
  const int mt = blockIdx.x >> 5, nt = blockIdx.x & 31;  // 16 x 32 tiles of 32x32
  const int row0 = mt * 32, col0 = nt * 32;
  const int rA = tid >> 3, gA = tid & 7;
  const int sA = (gA ^ (rA & 7)) * 8;
  const short* srcA = A + (size_t)(row0 + rA) * H_DIM + sA;
  const short* srcB = B + (size_t)(col0 + rA) * H_DIM + sA;
  const int NT = H_DIM / 64;
  const int rm = lane & 15, quad = lane >> 4;
  f32x4 acc = {};
  stage16(srcA, lds + tid * 8);
  stage16(srcB, lds + 2048 + tid * 8);
  __syncthreads();
  const int ra = wm * 16 + rm, rb = wn * 16 + rm;
  const int oa = ra * 64, ob = rb * 64;
  const int xa = (ra & 7), xb = (rb & 7);
  for (int kt = 0; kt < NT; kt++) {
    const int cur = kt & 1;
    if (kt + 1 < NT) {
      const int o = (kt + 1) * 64;
      short* nb = lds + (cur ^ 1) * 4096;
      stage16(srcA + o, nb + tid * 8);
      stage16(srcB + o, nb + 2048 + tid * 8);
    }
    const short* Ac = lds + cur * 4096;
    const short* Bc = Ac + 2048;
#pragma unroll
    for (int ks = 0; ks < 2; ks++) {
      const int kg = ks * 4 + quad;
      bf16x8f af = *(const bf16x8f*)&Ac[oa + ((kg ^ xa) << 3)];
      bf16x8f bf = *(const bf16x8f*)&Bc[ob + ((kg ^ xb) << 3)];
      acc = MFMA(af, bf, acc, 0, 0, 0);
    }
    if (kt + 1 < NT) __syncthreads();
  }
  int gc = col0 + wn * 16 + rm;
#pragma unroll
  for (int r = 0; r < 4; r++) {
    int gr = row0 + wm * 16 + quad * 4 + r;
    y[(size_t)gr * Y_DIM + gc] = acc[r];
  }
}

extern "C" void kernel_launch(void* const* d_in, const int* in_sizes, int n_in,
                              void* d_out, int out_size, void* d_ws, size_t ws_size,
                              hipStream_t stream) {
  const float* u  = (const float*)d_in[0];
  const float* du = (const float*)d_in[1];
  const float* W  = (const float*)d_in[2];
  const float* Bw = (const float*)d_in[3];
  const float* Cw = (const float*)d_in[4];
  const float* h  = (const float*)d_in[5];
  float* y = (float*)d_out;

  char* w = (char*)d_ws;
  size_t off = 0;
  short* Bwb  = (short*)(w + off); off += (size_t)H_DIM * K_CAT * sizeof(short);  // 6 MB
  short* Cwb  = (short*)(w + off); off += (size_t)Y_DIM * H_DIM * sizeof(short);  // 4 MB
  short* bb   = (short*)(w + off); off += (size_t)B_SZ * H_DIM * sizeof(short);   // 2 MB
  short* catb = (short*)(w + off); off += (size_t)B_SZ * K_CAT * sizeof(short);   // 1.5 MB
  float* wh   = (float*)(w + off); off += H_DIM * sizeof(float);
  float* wtp  = (float*)(w + off); off += 32 * H_DIM * sizeof(float);             // 256 KB
  if (ws_size < off) return;

  k1<<<1024, 256, 0, stream>>>(W, h, Bw, du, u, wh, wtp, Bwb, catb);
  k2<<<1024, 256, 0, stream>>>(catb, Bwb, h, wh, wtp, bb, Cw, Cwb);
  k3<<<512, 256, 0, stream>>>(bb, Cwb, y);
}

// Round 5
// 111.386 us; speedup vs baseline: 1.4116x; 1.1088x over previous
//
#include <hip/hip_runtime.h>
#include <hip/hip_bf16.h>

// Established: inputs f32, output f32. Threshold 0.038; absmax floor 0.0078 (1 bf16 ulp).
// Math: y = (rec + DELTA*(cat(du,u)@Bw^T)) @ Cw^T,  rec = h + 0.005*(W@h - W^T@h)
// (expm/inv series truncated at X^1; X^2+ terms <4e-5, validated r3-r9).
// r9: intra-kernel fusion catastrophic. r11: reg-direct low-grid GEMM regressed (occupancy).
// r13: fused single-pass W latency-serialized (46.8us @ 6% BW) -> two-pass W kept.
// r14 (=123.5us): r0 k1 + gl_lds/XOR-swizzle k2,k3 with 2-buf drain-0 loop.
// r15: k2/k3 K-loops -> 3-buffer rotation + counted s_waitcnt vmcnt(N) (T3/T4, m218) +
//   single raw s_barrier per kt (was 2 syncthreads = vmcnt(0) drain each kt, exposing the
//   full L2 round-trip per iteration). Stage(kt+2) issued at iter kt -> 2-deep hiding.

#define B_SZ 512
#define U_DIM 1024
#define DU_DIM 512
#define H_DIM 2048
#define Y_DIM 1024
#define K_CAT 1536
#define DELTA_F 0.01f

typedef __hip_bfloat16 bf16;
using bf16x8f = __attribute__((ext_vector_type(8))) short;
using f32x4   = __attribute__((ext_vector_type(4))) float;

__device__ __forceinline__ short f2bs(float x) {
  union { bf16 b; short s; } u; u.b = __float2bfloat16(x); return u.s;
}
__device__ __forceinline__ int4 pack8(const float4 v0, const float4 v1) {
  union { short s[8]; int4 i; } o;
  o.s[0] = f2bs(v0.x); o.s[1] = f2bs(v0.y); o.s[2] = f2bs(v0.z); o.s[3] = f2bs(v0.w);
  o.s[4] = f2bs(v1.x); o.s[5] = f2bs(v1.y); o.s[6] = f2bs(v1.z); o.s[7] = f2bs(v1.w);
  return o.i;
}

// async 16B global->LDS. LDS dest is wave-uniform base + lane*16 (linear in tid).
__device__ __forceinline__ void stage16(const void* g, void* l) {
  __builtin_amdgcn_global_load_lds(
      (const __attribute__((address_space(1))) unsigned int*)g,
      (__attribute__((address_space(3))) unsigned int*)l, 16, 0, 0);
}

#define NB   (H_DIM * K_CAT / 8)   // 393216 Bw granules
#define NCAT (B_SZ * K_CAT / 8)    //  98304 cat granules
#define NC   (Y_DIM * H_DIM / 8)   // 262144 Cw granules

// ---------------- K1: wh (0..511), wtp partials (512..767), Bw+cat cvt (768..1023) ----------------
__global__ __launch_bounds__(256) void k1(const float* __restrict__ W, const float* __restrict__ h,
                                          const float* __restrict__ Bw, const float* __restrict__ du,
                                          const float* __restrict__ u, float* __restrict__ wh,
                                          float* __restrict__ wtp, short* __restrict__ Bwb,
                                          short* __restrict__ catb) {
  const int b = blockIdx.x;
  if (b < 512) {  // wh[row] = dot(W[row,:], h)   (one shfl-reduce per ROW, at the end)
    const int lane = threadIdx.x & 63, wave = threadIdx.x >> 6;
    const int row = b * 4 + wave;
    const float* wr = W + (size_t)row * H_DIM;
    float s = 0.f;
#pragma unroll
    for (int it = 0; it < 8; it++) {
      int k = it * 256 + lane * 4;
      float4 a = *(const float4*)(wr + k);
      float4 hv = *(const float4*)(h + k);
      s += a.x * hv.x + a.y * hv.y + a.z * hv.z + a.w * hv.w;
    }
#pragma unroll
    for (int off = 32; off > 0; off >>= 1) s += __shfl_down(s, off);
    if (lane == 0) wh[row] = s;
  } else if (b < 768) {  // wtp[rowg][k] = sum over 64-row chunk of W[i][k]*h[i]  (no shfls)
    const int e = b - 512;
    const int colg = e & 7, rowg = e >> 3;
    const int k = colg * 256 + threadIdx.x;
    float s = 0.f;
    const float* base = W + (size_t)rowg * 64 * H_DIM + k;
#pragma unroll 8
    for (int i = 0; i < 64; i++) s += base[(size_t)i * H_DIM] * h[rowg * 64 + i];
    wtp[rowg * H_DIM + k] = s;
  } else {  // Bw, cat(du,u) -> bf16
    for (int g = (b - 768) * 256 + threadIdx.x; g < NB + NCAT; g += 256 * 256) {
      if (g < NB) {
        int e = g * 8;
        *(int4*)(Bwb + e) = pack8(*(const float4*)(Bw + e), *(const float4*)(Bw + e + 4));
      } else {
        int g2 = g - NB;
        int row = g2 / 192, c = g2 - row * 192;  // 192 granules per 1536-wide row
        const float* src = (c < 64) ? du + (size_t)row * DU_DIM + c * 8
                                    : u + (size_t)row * U_DIM + (c - 64) * 8;
        *(int4*)(catb + (size_t)row * K_CAT + c * 8) =
            pack8(*(const float4*)src, *(const float4*)(src + 4));
      }
    }
  }
}

#define MFMA __builtin_amdgcn_mfma_f32_16x16x32_bf16

// ---------------- K2: 512 GEMM blocks (32x64 tiles) + 512 Cw-cvt blocks (overlapped) ----------------
// bb = bf16(rec + DELTA*(catb @ Bwb^T)); 3-buf rotation, counted vmcnt, 1 barrier/kt.
__global__ __launch_bounds__(256) void k2(const short* __restrict__ catb, const short* __restrict__ Bwb,
                                          const float* __restrict__ h, const float* __restrict__ wh,
                                          const float* __restrict__ wtp, short* __restrict__ bb,
                                          const float* __restrict__ Cw, short* __restrict__ Cwb) {
  __shared__ __align__(16) short lds[3 * 6144];  // per buf: A 32x64 (2048) + B 64x64 (4096)
  __shared__ float recf[64];
  const int b = blockIdx.x;
  if (b >= 512) {  // Cw -> bf16 (consumed only by k3; hidden behind GEMM blocks)
    int g0 = (b - 512) * 256 + threadIdx.x;  // NC = 262144 = 2 * 131072
    int e = g0 * 8;
    *(int4*)(Cwb + e) = pack8(*(const float4*)(Cw + e), *(const float4*)(Cw + e + 4));
    e = (g0 + 131072) * 8;
    *(int4*)(Cwb + e) = pack8(*(const float4*)(Cw + e), *(const float4*)(Cw + e + 4));
    return;
  }
  const int tid = threadIdx.x;
  const int lane = tid & 63, wave = tid >> 6;
  const int wm = wave >> 1, wn = wave & 1;
  const int mt = b >> 5, nt = b & 31;  // 16 x 32 tiles of 32x64
  const int row0 = mt * 32, col0 = nt * 64;
  const int rA = tid >> 3, gA = tid & 7;
  const int sA = (gA ^ (rA & 7)) * 8;  // pre-swizzled source granule; (r+32)&7 == r&7
  const short* srcA  = catb + (size_t)(row0 + rA) * K_CAT + sA;
  const short* srcB1 = Bwb + (size_t)(col0 + rA) * K_CAT + sA;
  const short* srcB2 = Bwb + (size_t)(col0 + 32 + rA) * K_CAT + sA;
  const int NT = K_CAT / 64;  // 24
  const int rm = lane & 15, quad = lane >> 4;
  f32x4 acc[2] = {};
  // prologue: stage tiles 0,1 into bufs 0,1 (3 gl_lds per thread per tile)
#pragma unroll
  for (int t = 0; t < 2; t++) {
    short* nb = lds + t * 6144;
    const int o = t * 64;
    stage16(srcA + o,  nb + tid * 8);
    stage16(srcB1 + o, nb + 2048 + tid * 8);
    stage16(srcB2 + o, nb + 4096 + tid * 8);
  }
  const int ra = wm * 16 + rm;
  const int rb0 = wn * 32 + rm, rb1 = wn * 32 + 16 + rm;
  const int oa = ra * 64, ob0 = 2048 + rb0 * 64, ob1 = 2048 + rb1 * 64;
  const int xa = (ra & 7), xb0 = (rb0 & 7), xb1 = (rb1 & 7);
#pragma unroll
  for (int kt = 0; kt < NT; kt++) {
    // wait for tile kt only (tile kt+1's 3 loads may stay in flight); drain on last iter
    if (kt < NT - 1) asm volatile("s_waitcnt vmcnt(3)" ::: "memory");
    else             asm volatile("s_waitcnt vmcnt(0)" ::: "memory");
    __builtin_amdgcn_s_barrier();
    if (kt + 2 < NT) {  // stage tile kt+2 into buf freed at kt-1 (ordered by the barrier above)
      const int o = (kt + 2) * 64;
      short* nb = lds + ((kt + 2) % 3) * 6144;
      stage16(srcA + o,  nb + tid * 8);
      stage16(srcB1 + o, nb + 2048 + tid * 8);
      stage16(srcB2 + o, nb + 4096 + tid * 8);
    }
    const short* Ac = lds + (kt % 3) * 6144;
#pragma unroll
    for (int ks = 0; ks < 2; ks++) {
      const int kg = ks * 4 + quad;
      bf16x8f af  = *(const bf16x8f*)&Ac[oa + ((kg ^ xa) << 3)];
      bf16x8f bf0 = *(const bf16x8f*)&Ac[ob0 + ((kg ^ xb0) << 3)];
      bf16x8f bf1 = *(const bf16x8f*)&Ac[ob1 + ((kg ^ xb1) << 3)];
      acc[0] = MFMA(af, bf0, acc[0], 0, 0, 0);
      acc[1] = MFMA(af, bf1, acc[1], 0, 0, 0);
    }
  }
  if (tid < 64) {  // rec[c] = h[c] + 0.005*(wh[c] - sum_p wtp[p][c])
    int gc = col0 + tid;
    float s = 0.f;
#pragma unroll
    for (int p = 0; p < 32; p++) s += wtp[p * H_DIM + gc];
    recf[tid] = h[gc] + 0.005f * (wh[gc] - s);
  }
  __syncthreads();
#pragma unroll
  for (int j = 0; j < 2; j++) {
    int gc = col0 + wn * 32 + 16 * j + rm;
#pragma unroll
    for (int r = 0; r < 4; r++) {
      int gr = row0 + wm * 16 + quad * 4 + r;
      bb[(size_t)gr * H_DIM + gc] = f2bs(recf[gc - col0] + DELTA_F * acc[j][r]);
    }
  }
}

// ---------------- K3: 512 blocks, 32x32 tiles: y = bb @ Cwb^T (f32 out) ----------------
__global__ __launch_bounds__(256) void k3(const short* __restrict__ A, const short* __restrict__ B,
                                          float* __restrict__ y) {
  __shared__ __align__(16) short lds[3 * 4096];  // per buf: A 32x64 (2048) + B 32x64 (2048)
  const int tid = threadIdx.x;
  const int lane = tid & 63, wave = tid >> 6;
  const int wm = wave >> 1, wn = wave & 1;
  const int mt = blockIdx.x >> 5, nt = blockIdx.x & 31;  // 16 x 32 tiles of 32x32
  const int row0 = mt * 32, col0 = nt * 32;
  const int rA = tid >> 3, gA = tid & 7;
  const int sA = (gA ^ (rA & 7)) * 8;
  const short* srcA = A + (size_t)(row0 + rA) * H_DIM + sA;
  const short* srcB = B + (size_t)(col0 + rA) * H_DIM + sA;
  const int NT = H_DIM / 64;  // 32
  const int rm = lane & 15, quad = lane >> 4;
  f32x4 acc = {};
#pragma unroll
  for (int t = 0; t < 2; t++) {
    short* nb = lds + t * 4096;
    const int o = t * 64;
    stage16(srcA + o, nb + tid * 8);
    stage16(srcB + o, nb + 2048 + tid * 8);
  }
  const int ra = wm * 16 + rm, rb = wn * 16 + rm;
  const int oa = ra * 64, ob = 2048 + rb * 64;
  const int xa = (ra & 7), xb = (rb & 7);
#pragma unroll
  for (int kt = 0; kt < NT; kt++) {
    if (kt < NT - 1) asm volatile("s_waitcnt vmcnt(2)" ::: "memory");
    else             asm volatile("s_waitcnt vmcnt(0)" ::: "memory");
    __builtin_amdgcn_s_barrier();
    if (kt + 2 < NT) {
      const int o = (kt + 2) * 64;
      short* nb = lds + ((kt + 2) % 3) * 4096;
      stage16(srcA + o, nb + tid * 8);
      stage16(srcB + o, nb + 2048 + tid * 8);
    }
    const short* Ac = lds + (kt % 3) * 4096;
#pragma unroll
    for (int ks = 0; ks < 2; ks++) {
      const int kg = ks * 4 + quad;
      bf16x8f af = *(const bf16x8f*)&Ac[oa + ((kg ^ xa) << 3)];
      bf16x8f bf = *(const bf16x8f*)&Ac[ob + ((kg ^ xb) << 3)];
      acc = MFMA(af, bf, acc, 0, 0, 0);
    }
  }
  int gc = col0 + wn * 16 + rm;
#pragma unroll
  for (int r = 0; r < 4; r++) {
    int gr = row0 + wm * 16 + quad * 4 + r;
    y[(size_t)gr * Y_DIM + gc] = acc[r];
  }
}

extern "C" void kernel_launch(void* const* d_in, const int* in_sizes, int n_in,
                              void* d_out, int out_size, void* d_ws, size_t ws_size,
                              hipStream_t stream) {
  const float* u  = (const float*)d_in[0];
  const float* du = (const float*)d_in[1];
  const float* W  = (const float*)d_in[2];
  const float* Bw = (const float*)d_in[3];
  const float* Cw = (const float*)d_in[4];
  const float* h  = (const float*)d_in[5];
  float* y = (float*)d_out;

  char* w = (char*)d_ws;
  size_t off = 0;
  short* Bwb  = (short*)(w + off); off += (size_t)H_DIM * K_CAT * sizeof(short);  // 6 MB
  short* Cwb  = (short*)(w + off); off += (size_t)Y_DIM * H_DIM * sizeof(short);  // 4 MB
  short* bb   = (short*)(w + off); off += (size_t)B_SZ * H_DIM * sizeof(short);   // 2 MB
  short* catb = (short*)(w + off); off += (size_t)B_SZ * K_CAT * sizeof(short);   // 1.5 MB
  float* wh   = (float*)(w + off); off += H_DIM * sizeof(float);
  float* wtp  = (float*)(w + off); off += 32 * H_DIM * sizeof(float);             // 256 KB
  if (ws_size < off) return;

  k1<<<1024, 256, 0, stream>>>(W, h, Bw, du, u, wh, wtp, Bwb, catb);
  k2<<<1024, 256, 0, stream>>>(catb, Bwb, h, wh, wtp, bb, Cw, Cwb);
  k3<<<512, 256, 0, stream>>>(bb, Cwb, y);
}

// Round 6
// 110.781 us; speedup vs baseline: 1.4193x; 1.0055x over previous
//
#include <hip/hip_runtime.h>
#include <hip/hip_bf16.h>

// Established: inputs f32, output f32. Threshold 0.038; absmax floor 0.0078 (1 bf16 ulp).
// Math: y = (rec + DELTA*(cat(du,u)@Bw^T)) @ Cw^T,  rec = h + 0.005*(W@h - W^T@h)
// (expm/inv series truncated at X^1; X^2+ terms <4e-5, validated r3-r9).
// r9: intra-kernel fusion catastrophic. r11: reg-direct low-grid GEMM regressed (occupancy).
// r13: fused single-pass W latency-serialized -> two-pass W kept (L3 absorbs 2nd read).
// r15 (=111.4us): 3-buf rotation + counted vmcnt + 1 barrier/kt in k2/k3 (-12us vs drain-0).
// r16: pipeline depth 1 -> 2 tiles in flight (4 buffers; wait vmcnt(6)/(4) steady-state,
//   graded tail). Same reuse invariant as r15 (overwritten buf last read at kt-1, drained
//   before that iter's MFMAs, which precede the barrier). LDS 48/32 KB -> still 2 blk/CU.

#define B_SZ 512
#define U_DIM 1024
#define DU_DIM 512
#define H_DIM 2048
#define Y_DIM 1024
#define K_CAT 1536
#define DELTA_F 0.01f

typedef __hip_bfloat16 bf16;
using bf16x8f = __attribute__((ext_vector_type(8))) short;
using f32x4   = __attribute__((ext_vector_type(4))) float;

__device__ __forceinline__ short f2bs(float x) {
  union { bf16 b; short s; } u; u.b = __float2bfloat16(x); return u.s;
}
__device__ __forceinline__ int4 pack8(const float4 v0, const float4 v1) {
  union { short s[8]; int4 i; } o;
  o.s[0] = f2bs(v0.x); o.s[1] = f2bs(v0.y); o.s[2] = f2bs(v0.z); o.s[3] = f2bs(v0.w);
  o.s[4] = f2bs(v1.x); o.s[5] = f2bs(v1.y); o.s[6] = f2bs(v1.z); o.s[7] = f2bs(v1.w);
  return o.i;
}

// async 16B global->LDS. LDS dest is wave-uniform base + lane*16 (linear in tid).
__device__ __forceinline__ void stage16(const void* g, void* l) {
  __builtin_amdgcn_global_load_lds(
      (const __attribute__((address_space(1))) unsigned int*)g,
      (__attribute__((address_space(3))) unsigned int*)l, 16, 0, 0);
}

#define NB   (H_DIM * K_CAT / 8)   // 393216 Bw granules
#define NCAT (B_SZ * K_CAT / 8)    //  98304 cat granules
#define NC   (Y_DIM * H_DIM / 8)   // 262144 Cw granules

// ---------------- K1: wh (0..511), wtp partials (512..767), Bw+cat cvt (768..1023) ----------------
__global__ __launch_bounds__(256) void k1(const float* __restrict__ W, const float* __restrict__ h,
                                          const float* __restrict__ Bw, const float* __restrict__ du,
                                          const float* __restrict__ u, float* __restrict__ wh,
                                          float* __restrict__ wtp, short* __restrict__ Bwb,
                                          short* __restrict__ catb) {
  const int b = blockIdx.x;
  if (b < 512) {  // wh[row] = dot(W[row,:], h)   (one shfl-reduce per ROW, at the end)
    const int lane = threadIdx.x & 63, wave = threadIdx.x >> 6;
    const int row = b * 4 + wave;
    const float* wr = W + (size_t)row * H_DIM;
    float s = 0.f;
#pragma unroll
    for (int it = 0; it < 8; it++) {
      int k = it * 256 + lane * 4;
      float4 a = *(const float4*)(wr + k);
      float4 hv = *(const float4*)(h + k);
      s += a.x * hv.x + a.y * hv.y + a.z * hv.z + a.w * hv.w;
    }
#pragma unroll
    for (int off = 32; off > 0; off >>= 1) s += __shfl_down(s, off);
    if (lane == 0) wh[row] = s;
  } else if (b < 768) {  // wtp[rowg][k] = sum over 64-row chunk of W[i][k]*h[i]  (no shfls)
    const int e = b - 512;
    const int colg = e & 7, rowg = e >> 3;
    const int k = colg * 256 + threadIdx.x;
    float s = 0.f;
    const float* base = W + (size_t)rowg * 64 * H_DIM + k;
#pragma unroll 8
    for (int i = 0; i < 64; i++) s += base[(size_t)i * H_DIM] * h[rowg * 64 + i];
    wtp[rowg * H_DIM + k] = s;
  } else {  // Bw, cat(du,u) -> bf16
    for (int g = (b - 768) * 256 + threadIdx.x; g < NB + NCAT; g += 256 * 256) {
      if (g < NB) {
        int e = g * 8;
        *(int4*)(Bwb + e) = pack8(*(const float4*)(Bw + e), *(const float4*)(Bw + e + 4));
      } else {
        int g2 = g - NB;
        int row = g2 / 192, c = g2 - row * 192;  // 192 granules per 1536-wide row
        const float* src = (c < 64) ? du + (size_t)row * DU_DIM + c * 8
                                    : u + (size_t)row * U_DIM + (c - 64) * 8;
        *(int4*)(catb + (size_t)row * K_CAT + c * 8) =
            pack8(*(const float4*)src, *(const float4*)(src + 4));
      }
    }
  }
}

#define MFMA __builtin_amdgcn_mfma_f32_16x16x32_bf16

// ---------------- K2: 512 GEMM blocks (32x64 tiles) + 512 Cw-cvt blocks (overlapped) ----------------
// bb = bf16(rec + DELTA*(catb @ Bwb^T)); 4-buf rotation, 2-tile-deep counted vmcnt, 1 barrier/kt.
__global__ __launch_bounds__(256) void k2(const short* __restrict__ catb, const short* __restrict__ Bwb,
                                          const float* __restrict__ h, const float* __restrict__ wh,
                                          const float* __restrict__ wtp, short* __restrict__ bb,
                                          const float* __restrict__ Cw, short* __restrict__ Cwb) {
  __shared__ __align__(16) short lds[4 * 6144];  // per buf: A 32x64 (2048) + B 64x64 (4096)
  __shared__ float recf[64];
  const int b = blockIdx.x;
  if (b >= 512) {  // Cw -> bf16 (consumed only by k3; hidden behind GEMM blocks)
    int g0 = (b - 512) * 256 + threadIdx.x;  // NC = 262144 = 2 * 131072
    int e = g0 * 8;
    *(int4*)(Cwb + e) = pack8(*(const float4*)(Cw + e), *(const float4*)(Cw + e + 4));
    e = (g0 + 131072) * 8;
    *(int4*)(Cwb + e) = pack8(*(const float4*)(Cw + e), *(const float4*)(Cw + e + 4));
    return;
  }
  const int tid = threadIdx.x;
  const int lane = tid & 63, wave = tid >> 6;
  const int wm = wave >> 1, wn = wave & 1;
  const int mt = b >> 5, nt = b & 31;  // 16 x 32 tiles of 32x64
  const int row0 = mt * 32, col0 = nt * 64;
  const int rA = tid >> 3, gA = tid & 7;
  const int sA = (gA ^ (rA & 7)) * 8;  // pre-swizzled source granule; (r+32)&7 == r&7
  const short* srcA  = catb + (size_t)(row0 + rA) * K_CAT + sA;
  const short* srcB1 = Bwb + (size_t)(col0 + rA) * K_CAT + sA;
  const short* srcB2 = Bwb + (size_t)(col0 + 32 + rA) * K_CAT + sA;
  const int NT = K_CAT / 64;  // 24
  const int rm = lane & 15, quad = lane >> 4;
  f32x4 acc[2] = {};
  // prologue: stage tiles 0,1,2 into bufs 0,1,2 (3 gl_lds per thread per tile)
#pragma unroll
  for (int t = 0; t < 3; t++) {
    short* nb = lds + t * 6144;
    const int o = t * 64;
    stage16(srcA + o,  nb + tid * 8);
    stage16(srcB1 + o, nb + 2048 + tid * 8);
    stage16(srcB2 + o, nb + 4096 + tid * 8);
  }
  const int ra = wm * 16 + rm;
  const int rb0 = wn * 32 + rm, rb1 = wn * 32 + 16 + rm;
  const int oa = ra * 64, ob0 = 2048 + rb0 * 64, ob1 = 2048 + rb1 * 64;
  const int xa = (ra & 7), xb0 = (rb0 & 7), xb1 = (rb1 & 7);
#pragma unroll
  for (int kt = 0; kt < NT; kt++) {
    // wait for tile kt only; up to 2 later tiles (6 loads) stay in flight. Graded tail.
    if (kt <= NT - 3)      asm volatile("s_waitcnt vmcnt(6)" ::: "memory");
    else if (kt == NT - 2) asm volatile("s_waitcnt vmcnt(3)" ::: "memory");
    else                   asm volatile("s_waitcnt vmcnt(0)" ::: "memory");
    __builtin_amdgcn_s_barrier();
    if (kt + 3 < NT) {  // stage tile kt+3 into buf (kt-1)&3 (read drained at kt-1, pre-barrier)
      const int o = (kt + 3) * 64;
      short* nb = lds + ((kt + 3) & 3) * 6144;
      stage16(srcA + o,  nb + tid * 8);
      stage16(srcB1 + o, nb + 2048 + tid * 8);
      stage16(srcB2 + o, nb + 4096 + tid * 8);
    }
    const short* Ac = lds + (kt & 3) * 6144;
#pragma unroll
    for (int ks = 0; ks < 2; ks++) {
      const int kg = ks * 4 + quad;
      bf16x8f af  = *(const bf16x8f*)&Ac[oa + ((kg ^ xa) << 3)];
      bf16x8f bf0 = *(const bf16x8f*)&Ac[ob0 + ((kg ^ xb0) << 3)];
      bf16x8f bf1 = *(const bf16x8f*)&Ac[ob1 + ((kg ^ xb1) << 3)];
      acc[0] = MFMA(af, bf0, acc[0], 0, 0, 0);
      acc[1] = MFMA(af, bf1, acc[1], 0, 0, 0);
    }
  }
  if (tid < 64) {  // rec[c] = h[c] + 0.005*(wh[c] - sum_p wtp[p][c])
    int gc = col0 + tid;
    float s = 0.f;
#pragma unroll
    for (int p = 0; p < 32; p++) s += wtp[p * H_DIM + gc];
    recf[tid] = h[gc] + 0.005f * (wh[gc] - s);
  }
  __syncthreads();
#pragma unroll
  for (int j = 0; j < 2; j++) {
    int gc = col0 + wn * 32 + 16 * j + rm;
#pragma unroll
    for (int r = 0; r < 4; r++) {
      int gr = row0 + wm * 16 + quad * 4 + r;
      bb[(size_t)gr * H_DIM + gc] = f2bs(recf[gc - col0] + DELTA_F * acc[j][r]);
    }
  }
}

// ---------------- K3: 512 blocks, 32x32 tiles: y = bb @ Cwb^T (f32 out) ----------------
__global__ __launch_bounds__(256) void k3(const short* __restrict__ A, const short* __restrict__ B,
                                          float* __restrict__ y) {
  __shared__ __align__(16) short lds[4 * 4096];  // per buf: A 32x64 (2048) + B 32x64 (2048)
  const int tid = threadIdx.x;
  const int lane = tid & 63, wave = tid >> 6;
  const int wm = wave >> 1, wn = wave & 1;
  const int mt = blockIdx.x >> 5, nt = blockIdx.x & 31;  // 16 x 32 tiles of 32x32
  const int row0 = mt * 32, col0 = nt * 32;
  const int rA = tid >> 3, gA = tid & 7;
  const int sA = (gA ^ (rA & 7)) * 8;
  const short* srcA = A + (size_t)(row0 + rA) * H_DIM + sA;
  const short* srcB = B + (size_t)(col0 + rA) * H_DIM + sA;
  const int NT = H_DIM / 64;  // 32
  const int rm = lane & 15, quad = lane >> 4;
  f32x4 acc = {};
#pragma unroll
  for (int t = 0; t < 3; t++) {
    short* nb = lds + t * 4096;
    const int o = t * 64;
    stage16(srcA + o, nb + tid * 8);
    stage16(srcB + o, nb + 2048 + tid * 8);
  }
  const int ra = wm * 16 + rm, rb = wn * 16 + rm;
  const int oa = ra * 64, ob = 2048 + rb * 64;
  const int xa = (ra & 7), xb = (rb & 7);
#pragma unroll
  for (int kt = 0; kt < NT; kt++) {
    if (kt <= NT - 3)      asm volatile("s_waitcnt vmcnt(4)" ::: "memory");
    else if (kt == NT - 2) asm volatile("s_waitcnt vmcnt(2)" ::: "memory");
    else                   asm volatile("s_waitcnt vmcnt(0)" ::: "memory");
    __builtin_amdgcn_s_barrier();
    if (kt + 3 < NT) {
      const int o = (kt + 3) * 64;
      short* nb = lds + ((kt + 3) & 3) * 4096;
      stage16(srcA + o, nb + tid * 8);
      stage16(srcB + o, nb + 2048 + tid * 8);
    }
    const short* Ac = lds + (kt & 3) * 4096;
#pragma unroll
    for (int ks = 0; ks < 2; ks++) {
      const int kg = ks * 4 + quad;
      bf16x8f af = *(const bf16x8f*)&Ac[oa + ((kg ^ xa) << 3)];
      bf16x8f bf = *(const bf16x8f*)&Ac[ob + ((kg ^ xb) << 3)];
      acc = MFMA(af, bf, acc, 0, 0, 0);
    }
  }
  int gc = col0 + wn * 16 + rm;
#pragma unroll
  for (int r = 0; r < 4; r++) {
    int gr = row0 + wm * 16 + quad * 4 + r;
    y[(size_t)gr * Y_DIM + gc] = acc[r];
  }
}

extern "C" void kernel_launch(void* const* d_in, const int* in_sizes, int n_in,
                              void* d_out, int out_size, void* d_ws, size_t ws_size,
                              hipStream_t stream) {
  const float* u  = (const float*)d_in[0];
  const float* du = (const float*)d_in[1];
  const float* W  = (const float*)d_in[2];
  const float* Bw = (const float*)d_in[3];
  const float* Cw = (const float*)d_in[4];
  const float* h  = (const float*)d_in[5];
  float* y = (float*)d_out;

  char* w = (char*)d_ws;
  size_t off = 0;
  short* Bwb  = (short*)(w + off); off += (size_t)H_DIM * K_CAT * sizeof(short);  // 6 MB
  short* Cwb  = (short*)(w + off); off += (size_t)Y_DIM * H_DIM * sizeof(short);  // 4 MB
  short* bb   = (short*)(w + off); off += (size_t)B_SZ * H_DIM * sizeof(short);   // 2 MB
  short* catb = (short*)(w + off); off += (size_t)B_SZ * K_CAT * sizeof(short);   // 1.5 MB
  float* wh   = (float*)(w + off); off += H_DIM * sizeof(float);
  float* wtp  = (float*)(w + off); off += 32 * H_DIM * sizeof(float);             // 256 KB
  if (ws_size < off) return;

  k1<<<1024, 256, 0, stream>>>(W, h, Bw, du, u, wh, wtp, Bwb, catb);
  k2<<<1024, 256, 0, stream>>>(catb, Bwb, h, wh, wtp, bb, Cw, Cwb);
  k3<<<512, 256, 0, stream>>>(bb, Cwb, y);
}